// Round 3
// baseline (2697.646 us; speedup 1.0000x reference)
//
#include <hip/hip_runtime.h>
#include <hip/hip_bf16.h>

#define NND 50000
#define NED 800000
#define NGR 64
#define EPSV 1e-5f

// ---------------- K1: dilated conv1d, 3 branches ----------------
// X[br][p][96] = conv_b[br][o] + sum_{k,c} w[br][o][c][k] * nf[p+(k-1)(br+1)][c]
__global__ void conv_kernel(const float* __restrict__ nf, const float* __restrict__ cw,
                            const float* __restrict__ cb, float* __restrict__ X)
{
    __shared__ __align__(16) float wl[3 * 128 * 32];   // [k][c][j]
    const int t  = threadIdx.x;
    const int og = blockIdx.y;   // 0..2 (group of 32 out channels)
    const int br = blockIdx.z;   // 0..2
    for (int l = t; l < 3 * 128 * 32; l += 256) {
        int j = l & 31; int c = (l >> 5) & 127; int k = l >> 12;
        wl[l] = cw[(((size_t)br * 96 + og * 32 + j) * 128 + c) * 3 + k];
    }
    __syncthreads();
    int p = blockIdx.x * 256 + t;
    if (p >= NND) return;
    float acc[32];
#pragma unroll
    for (int j = 0; j < 32; j++) acc[j] = cb[br * 96 + og * 32 + j];
    const int d = br + 1;
    for (int k = 0; k < 3; k++) {
        int pp = p + (k - 1) * d;
        if (pp < 0 || pp >= NND) continue;
        const float4* row = (const float4*)(nf + (size_t)pp * 128);
        for (int c4 = 0; c4 < 32; c4++) {
            float4 u = row[c4];
            float f[4] = {u.x, u.y, u.z, u.w};
#pragma unroll
            for (int cc = 0; cc < 4; cc++) {
                const float4* wv = (const float4*)&wl[((k * 128) + (c4 * 4 + cc)) * 32];
#pragma unroll
                for (int jj = 0; jj < 8; jj++) {
                    float4 w4 = wv[jj];
                    acc[jj * 4 + 0] += f[cc] * w4.x;
                    acc[jj * 4 + 1] += f[cc] * w4.y;
                    acc[jj * 4 + 2] += f[cc] * w4.z;
                    acc[jj * 4 + 3] += f[cc] * w4.w;
                }
            }
        }
    }
    float* xo = X + (size_t)br * NND * 96 + (size_t)p * 96 + og * 32;
#pragma unroll
    for (int j = 0; j < 32; j++) xo[j] = acc[j];
}

// ---------------- K2: Y = relu(X_i)+X_{i+1} + BN1 stats ----------------
__global__ void y_stats_kernel(const float* __restrict__ X, float* __restrict__ Y,
                               float* __restrict__ st1)
{
    __shared__ float ls[96], lq[96];
    int t = threadIdx.x;
    if (t < 96) { ls[t] = 0.f; lq[t] = 0.f; }
    __syncthreads();
    int br = blockIdx.y; int ip1 = (br + 1) % 3;
    const size_t NM = (size_t)NND * 96;
    size_t base = (size_t)blockIdx.x * 6144;
    for (int q = 0; q < 24; q++) {
        size_t idx = base + q * 256 + t;
        if (idx < NM) {
            float a = X[(size_t)br * NM + idx]; a = a > 0.f ? a : 0.f;
            float y = a + X[(size_t)ip1 * NM + idx];
            Y[(size_t)br * NM + idx] = y;
            int o = (int)(idx % 96);
            atomicAdd(&ls[o], y);
            atomicAdd(&lq[o], y * y);
        }
    }
    __syncthreads();
    if (t < 96) {
        unsafeAtomicAdd(&st1[br * 96 + t], ls[t]);
        unsafeAtomicAdd(&st1[288 + br * 96 + t], lq[t]);
    }
}

// ---------------- BN finalize: scale/shift from (sum,sumsq) ----------------
__global__ void bn_finalize_kernel(const float* __restrict__ st, const float* __restrict__ g,
                                   const float* __restrict__ b,
                                   float* __restrict__ sc, float* __restrict__ sh,
                                   int C, int gmod)
{
    int t = threadIdx.x;
    if (t >= C) return;
    float mean = st[t] / (float)NND;
    float var  = st[C + t] / (float)NND - mean * mean;
    float rs = rsqrtf(var + EPSV);
    float gg = g[t % gmod], bb = b[t % gmod];
    float s = gg * rs;
    sc[t] = s; sh[t] = bb - mean * s;
}

// ---------------- K4: gather+affine+weight -> atomic scatter (96ch, 3 branches) ----
__global__ void gather_bn_kernel(const float* __restrict__ Y, const float* __restrict__ sc1,
                                 const float* __restrict__ sh1,
                                 const int* __restrict__ src, const int* __restrict__ dst,
                                 const float* __restrict__ ew, float* __restrict__ AGG)
{
    long long id = (long long)blockIdx.x * 256 + threadIdx.x;
    if (id >= (long long)NED * 96) return;
    int br = blockIdx.y;
    int e = (int)(id / 96); int c = (int)(id % 96);
    int s = src[e], d0 = dst[e];
    float w = ew[e];
    const size_t NM = (size_t)NND * 96;
    float v = (Y[(size_t)br * NM + (size_t)s * 96 + c] * sc1[br * 96 + c] + sh1[br * 96 + c]) * w;
    unsafeAtomicAdd(&AGG[(size_t)br * NM + (size_t)d0 * 96 + c], v);
}

// ---------------- generic small matmul + bias + relu ----------------
__global__ void matmul_relu_kernel(const float* __restrict__ in, const float* __restrict__ W,
                                   const float* __restrict__ bias, float* __restrict__ out,
                                   int Cin, int Cout)
{
    int id = blockIdx.x * 256 + threadIdx.x;
    if (id >= NND * Cout) return;
    int p = id / Cout, o = id % Cout;
    float acc = bias[o];
    const float* row = in + (size_t)p * Cin;
    for (int c = 0; c < Cin; c++) acc += row[c] * W[c * Cout + o];
    out[id] = acc > 0.f ? acc : 0.f;
}

// ---------------- K6: press conv (3ch,K=3,SAME over 54) + BN2 stats ----------------
__global__ void press_stats_kernel(const float* __restrict__ H2, const float* __restrict__ pw,
                                   const float* __restrict__ pb, float* __restrict__ PRS,
                                   float* __restrict__ st2)
{
    __shared__ float ls[54], lq[54];
    int t = threadIdx.x;
    if (t < 54) { ls[t] = 0.f; lq[t] = 0.f; }
    __syncthreads();
    float pwf[9];
#pragma unroll
    for (int q = 0; q < 9; q++) pwf[q] = pw[q];
    float pbf = pb[0];
    const size_t NM = (size_t)NND * 54;
    size_t base = (size_t)blockIdx.x * 6912;
    for (int q = 0; q < 27; q++) {
        size_t idx = base + q * 256 + t;
        if (idx < NM) {
            int p = (int)(idx / 54), h = (int)(idx % 54);
            float sum = pbf;
#pragma unroll
            for (int i = 0; i < 3; i++)
#pragma unroll
                for (int k = 0; k < 3; k++) {
                    int hh = h + k - 1;
                    if (hh >= 0 && hh < 54)
                        sum += pwf[i * 3 + k] * H2[(size_t)i * NM + (size_t)p * 54 + hh];
                }
            PRS[idx] = sum;
            atomicAdd(&ls[h], sum); atomicAdd(&lq[h], sum * sum);
        }
    }
    __syncthreads();
    if (t < 54) {
        unsafeAtomicAdd(&st2[t], ls[t]);
        unsafeAtomicAdd(&st2[54 + t], lq[t]);
    }
}

// ---------------- K8: emd = affine(pressed); write fp32 out + keep fp32 ----------------
__global__ void emd_kernel(float* __restrict__ PRS, const float* __restrict__ sc2,
                           const float* __restrict__ sh2, float* __restrict__ outp)
{
    int id = blockIdx.x * 256 + threadIdx.x;
    if (id >= NND * 54) return;
    int h = id % 54;
    float v = PRS[id] * sc2[h] + sh2[h];
    PRS[id] = v;
    outp[id] = v;
}

// ---------------- generic gather-scatter (templated channel count) ----------------
template <int C>
__global__ void gather_kernel(const float* __restrict__ in, const int* __restrict__ src,
                              const int* __restrict__ dst, const float* __restrict__ ew,
                              float* __restrict__ agg)
{
    long long id = (long long)blockIdx.x * 256 + threadIdx.x;
    if (id >= (long long)NED * C) return;
    int e = (int)(id / C); int c = (int)(id % C);
    float v = in[(size_t)src[e] * C + c] * ew[e];
    unsafeAtomicAdd(&agg[(size_t)dst[e] * C + c], v);
}

// ---------------- K15: graph pooling of concat(h1,h2,h3) ----------------
__global__ void pool_kernel(const float* __restrict__ H1, const float* __restrict__ H2j,
                            const float* __restrict__ H3, const int* __restrict__ gid,
                            float* __restrict__ HG)
{
    int id = blockIdx.x * 256 + threadIdx.x;
    if (id >= NND * 75) return;
    int p = id / 75, c = id % 75;
    float v;
    if (c < 34)      v = H1[(size_t)p * 34 + c];
    else if (c < 59) v = H2j[(size_t)p * 25 + (c - 34)];
    else             v = H3[(size_t)p * 16 + (c - 59)];
    unsafeAtomicAdd(&HG[gid[p] * 75 + c], v);
}

// ---------------- K16: BN3 + cls matmuls, single block ----------------
__global__ void final_kernel(const float* __restrict__ HG, const float* __restrict__ g3,
                             const float* __restrict__ b3,
                             const float* __restrict__ w1, const float* __restrict__ b1,
                             const float* __restrict__ w2, const float* __restrict__ b2,
                             float* __restrict__ outp)
{
    __shared__ float hg[64 * 75];
    __shared__ float o1[64 * 120];
    __shared__ float sc[75], sh[75];
    int t = threadIdx.x;   // 512
    for (int idx = t; idx < 64 * 75; idx += 512) hg[idx] = HG[idx];
    __syncthreads();
    if (t < 75) {
        float s = 0.f, q = 0.f;
        for (int r = 0; r < 64; r++) { float v = hg[r * 75 + t]; s += v; q += v * v; }
        float m = s / 64.f, var = q / 64.f - m * m;
        float rs = rsqrtf(var + EPSV);
        float scale = g3[t] * rs;
        sc[t] = scale; sh[t] = b3[t] - m * scale;
    }
    __syncthreads();
    for (int idx = t; idx < 64 * 75; idx += 512) { int c = idx % 75; hg[idx] = hg[idx] * sc[c] + sh[c]; }
    __syncthreads();
    for (int idx = t; idx < 64 * 120; idx += 512) {
        int r = idx / 120, o = idx % 120;
        float a = b1[o];
        for (int c = 0; c < 75; c++) a += hg[r * 75 + c] * w1[c * 120 + o];
        o1[idx] = a;
    }
    __syncthreads();
    for (int idx = t; idx < 640; idx += 512) {
        int r = idx / 10, o = idx % 10;
        float a = b2[o];
        for (int k = 0; k < 120; k++) a += o1[r * 120 + k] * w2[k * 10 + o];
        outp[idx] = a;
    }
}

extern "C" void kernel_launch(void* const* d_in, const int* in_sizes, int n_in,
                              void* d_out, int out_size, void* d_ws, size_t ws_size,
                              hipStream_t stream)
{
    (void)in_sizes; (void)n_in; (void)out_size;
    const float* nf     = (const float*)d_in[0];
    const float* ew     = (const float*)d_in[1];
    const float* conv_w = (const float*)d_in[2];
    const float* conv_b = (const float*)d_in[3];
    const float* gcn_w  = (const float*)d_in[4];
    const float* gcn_b  = (const float*)d_in[5];
    const float* bn1_g = (const float*)d_in[6],  *bn1_b = (const float*)d_in[7];
    const float* bn2_g = (const float*)d_in[8],  *bn2_b = (const float*)d_in[9];
    const float* bn3_g = (const float*)d_in[10], *bn3_b = (const float*)d_in[11];
    const float* press_w = (const float*)d_in[12], *press_b = (const float*)d_in[13];
    const float* jk_w1 = (const float*)d_in[14], *jk_b1 = (const float*)d_in[15];
    const float* jk_w2 = (const float*)d_in[16], *jk_b2 = (const float*)d_in[17];
    const float* jk_w3 = (const float*)d_in[18], *jk_b3 = (const float*)d_in[19];
    const float* cls1_w = (const float*)d_in[20], *cls1_b = (const float*)d_in[21];
    const float* cls2_w = (const float*)d_in[22], *cls2_b = (const float*)d_in[23];
    const int* esrc = (const int*)d_in[24];
    const int* edst = (const int*)d_in[25];
    const int* gid  = (const int*)d_in[26];
    float* out = (float*)d_out;   // fp32: reference outputs are jnp.float32

    float* ws = (float*)d_ws;
    const size_t NM = (size_t)NND * 96;
    const size_t N54 = (size_t)NND * 54;
    float* X   = ws;                 // 3*NM   (aliased later: AGG)
    float* Y   = X + 3 * NM;         // 3*NM   (aliased later: jk buffers)
    float* H2c = Y + 3 * NM;         // 3*N54
    float* PRS = H2c + 3 * N54;      // N54
    float* ST1 = PRS + N54;          // 576
    float* SC1 = ST1 + 576;          // 288
    float* SH1 = SC1 + 288;          // 288
    float* ST2 = SH1 + 288;          // 108
    float* SC2 = ST2 + 108;          // 54
    float* SH2 = SC2 + 54;           // 54
    float* HG  = SH2 + 54;           // 4800
    size_t need = (size_t)(HG + 4800 - ws) * sizeof(float);
    if (ws_size < need) return;      // ws too small -> fail loudly in validation

    // aliases
    float* AGG  = X;
    float* AGG1 = Y;                           // N*54
    float* H1j  = AGG1 + N54;                  // N*34
    float* AGG2 = H1j + (size_t)NND * 34;      // N*34
    float* H2j  = AGG2 + (size_t)NND * 34;     // N*25
    float* AGG3 = H2j + (size_t)NND * 25;      // N*25
    float* H3j  = AGG3 + (size_t)NND * 25;     // N*16

    // zero stats + HG (contiguous block of 6168 floats starting at ST1)
    hipMemsetAsync(ST1, 0, 6168 * sizeof(float), stream);

    // K1: dilated convs
    conv_kernel<<<dim3((NND + 255) / 256, 3, 3), 256, 0, stream>>>(nf, conv_w, conv_b, X);

    // K2/K3: Y + BN1
    y_stats_kernel<<<dim3((int)((NM + 6143) / 6144), 3), 256, 0, stream>>>(X, Y, ST1);
    bn_finalize_kernel<<<1, 512, 0, stream>>>(ST1, bn1_g, bn1_b, SC1, SH1, 288, 96);

    // K4: GCN aggregate (X region reused as AGG)
    hipMemsetAsync(AGG, 0, 3 * NM * sizeof(float), stream);
    gather_bn_kernel<<<dim3(300000, 3), 256, 0, stream>>>(Y, SC1, SH1, esrc, edst, ew, AGG);

    // K5: GCN matmul + relu per branch
    for (int i = 0; i < 3; i++)
        matmul_relu_kernel<<<(int)((N54 + 255) / 256), 256, 0, stream>>>(
            AGG + (size_t)i * NM, gcn_w + (size_t)i * 96 * 54, gcn_b + i * 54,
            H2c + (size_t)i * N54, 96, 54);

    // K6/K7/K8: press + BN2 + emd out (fp32, at element offset 640 = after logits)
    press_stats_kernel<<<(int)((N54 + 6911) / 6912), 256, 0, stream>>>(H2c, press_w, press_b, PRS, ST2);
    bn_finalize_kernel<<<1, 512, 0, stream>>>(ST2, bn2_g, bn2_b, SC2, SH2, 54, 54);
    emd_kernel<<<(int)((N54 + 255) / 256), 256, 0, stream>>>(PRS, SC2, SH2, out + 640);

    // JK layer 1 (Y region dead -> jk buffers)
    hipMemsetAsync(AGG1, 0, N54 * sizeof(float), stream);
    gather_kernel<54><<<168750, 256, 0, stream>>>(PRS, esrc, edst, ew, AGG1);
    matmul_relu_kernel<<<(NND * 34 + 255) / 256, 256, 0, stream>>>(AGG1, jk_w1, jk_b1, H1j, 54, 34);

    // JK layer 2
    hipMemsetAsync(AGG2, 0, (size_t)NND * 34 * sizeof(float), stream);
    gather_kernel<34><<<106250, 256, 0, stream>>>(H1j, esrc, edst, ew, AGG2);
    matmul_relu_kernel<<<(NND * 25 + 255) / 256, 256, 0, stream>>>(AGG2, jk_w2, jk_b2, H2j, 34, 25);

    // JK layer 3
    hipMemsetAsync(AGG3, 0, (size_t)NND * 25 * sizeof(float), stream);
    gather_kernel<25><<<78125, 256, 0, stream>>>(H2j, esrc, edst, ew, AGG3);
    matmul_relu_kernel<<<(NND * 16 + 255) / 256, 256, 0, stream>>>(AGG3, jk_w3, jk_b3, H3j, 25, 16);

    // pooling + final
    pool_kernel<<<(NND * 75 + 255) / 256, 256, 0, stream>>>(H1j, H2j, H3j, gid, HG);
    final_kernel<<<1, 512, 0, stream>>>(HG, bn3_g, bn3_b, cls1_w, cls1_b, cls2_w, cls2_b, out);
}

// Round 4
// 1800.967 us; speedup vs baseline: 1.4979x; 1.4979x over previous
//
#include <hip/hip_runtime.h>
#include <hip/hip_bf16.h>

#define NND 50000
#define NED 800000
#define NGR 64
#define EPSV 1e-5f

// ---------------- CSR build: histogram / scan / fill ----------------
__global__ void hist_kernel(const int* __restrict__ dst, int* __restrict__ cnt)
{
    int e = blockIdx.x * 256 + threadIdx.x;
    if (e < NED) atomicAdd(&cnt[dst[e]], 1);
}

__global__ void scan_kernel(const int* __restrict__ cnt, int* __restrict__ rowptr,
                            int* __restrict__ cursor)
{
    __shared__ int buf[1024];
    __shared__ int carry;
    int t = threadIdx.x;
    if (t == 0) carry = 0;
    __syncthreads();
    for (int base = 0; base < NND; base += 1024) {
        int v = (base + t < NND) ? cnt[base + t] : 0;
        buf[t] = v;
        __syncthreads();
        for (int off = 1; off < 1024; off <<= 1) {
            int x = (t >= off) ? buf[t - off] : 0;
            __syncthreads();
            buf[t] += x;
            __syncthreads();
        }
        int excl = buf[t] - v + carry;
        if (base + t < NND) { rowptr[base + t] = excl; cursor[base + t] = excl; }
        __syncthreads();
        if (t == 0) carry += buf[1023];
        __syncthreads();
    }
    if (t == 0) rowptr[NND] = carry;
}

__global__ void fill_kernel(const int* __restrict__ src, const int* __restrict__ dst,
                            const float* __restrict__ ew, int* __restrict__ cursor,
                            int* __restrict__ csrs, float* __restrict__ csrw)
{
    int e = blockIdx.x * 256 + threadIdx.x;
    if (e < NED) {
        int pos = atomicAdd(&cursor[dst[e]], 1);
        csrs[pos] = src[e];
        csrw[pos] = ew[e];
    }
}

// ---------------- K1: dilated conv1d, 3 branches ----------------
__global__ void conv_kernel(const float* __restrict__ nf, const float* __restrict__ cw,
                            const float* __restrict__ cb, float* __restrict__ X)
{
    __shared__ __align__(16) float wl[3 * 128 * 32];   // [k][c][j]
    const int t  = threadIdx.x;
    const int og = blockIdx.y;   // 0..2 (group of 32 out channels)
    const int br = blockIdx.z;   // 0..2
    for (int l = t; l < 3 * 128 * 32; l += 256) {
        int j = l & 31; int c = (l >> 5) & 127; int k = l >> 12;
        wl[l] = cw[(((size_t)br * 96 + og * 32 + j) * 128 + c) * 3 + k];
    }
    __syncthreads();
    int p = blockIdx.x * 256 + t;
    if (p >= NND) return;
    float acc[32];
#pragma unroll
    for (int j = 0; j < 32; j++) acc[j] = cb[br * 96 + og * 32 + j];
    const int d = br + 1;
    for (int k = 0; k < 3; k++) {
        int pp = p + (k - 1) * d;
        if (pp < 0 || pp >= NND) continue;
        const float4* row = (const float4*)(nf + (size_t)pp * 128);
        for (int c4 = 0; c4 < 32; c4++) {
            float4 u = row[c4];
            float f[4] = {u.x, u.y, u.z, u.w};
#pragma unroll
            for (int cc = 0; cc < 4; cc++) {
                const float4* wv = (const float4*)&wl[((k * 128) + (c4 * 4 + cc)) * 32];
#pragma unroll
                for (int jj = 0; jj < 8; jj++) {
                    float4 w4 = wv[jj];
                    acc[jj * 4 + 0] += f[cc] * w4.x;
                    acc[jj * 4 + 1] += f[cc] * w4.y;
                    acc[jj * 4 + 2] += f[cc] * w4.z;
                    acc[jj * 4 + 3] += f[cc] * w4.w;
                }
            }
        }
    }
    float* xo = X + (size_t)br * NND * 96 + (size_t)p * 96 + og * 32;
#pragma unroll
    for (int j = 0; j < 32; j++) xo[j] = acc[j];
}

// ---------------- K2: Y = relu(X_i)+X_{i+1} + BN1 stats (register accum) ----------
// block = 384 (96 channels x 4 row-subgroups), 64 rows per block
__global__ void y_stats_kernel(const float* __restrict__ X, float* __restrict__ Y,
                               float* __restrict__ st1)
{
    __shared__ float ls[384], lq[384];
    int t = threadIdx.x;
    int br = blockIdx.y, ip1 = (br + 1) % 3;
    int c = t % 96, rsub = t / 96;
    const size_t NM = (size_t)NND * 96;
    int r0 = blockIdx.x * 64;
    int rend = r0 + 64 < NND ? r0 + 64 : NND;
    float s = 0.f, q = 0.f;
    const float* Xa = X + (size_t)br * NM;
    const float* Xb = X + (size_t)ip1 * NM;
    float* Yb = Y + (size_t)br * NM;
    for (int r = r0 + rsub; r < rend; r += 4) {
        size_t idx = (size_t)r * 96 + c;
        float a = Xa[idx]; a = a > 0.f ? a : 0.f;
        float y = a + Xb[idx];
        Yb[idx] = y;
        s += y; q += y * y;
    }
    ls[t] = s; lq[t] = q;
    __syncthreads();
    if (t < 96) {
        s = ls[t] + ls[t + 96] + ls[t + 192] + ls[t + 288];
        q = lq[t] + lq[t + 96] + lq[t + 192] + lq[t + 288];
        unsafeAtomicAdd(&st1[br * 96 + t], s);
        unsafeAtomicAdd(&st1[288 + br * 96 + t], q);
    }
}

// ---------------- BN finalize: scale/shift from (sum,sumsq) ----------------
__global__ void bn_finalize_kernel(const float* __restrict__ st, const float* __restrict__ g,
                                   const float* __restrict__ b,
                                   float* __restrict__ sc, float* __restrict__ sh,
                                   int C, int gmod)
{
    int t = threadIdx.x;
    if (t >= C) return;
    float mean = st[t] / (float)NND;
    float var  = st[C + t] / (float)NND - mean * mean;
    float rs = rsqrtf(var + EPSV);
    float gg = g[t % gmod], bb = b[t % gmod];
    float s = gg * rs;
    sc[t] = s; sh[t] = bb - mean * s;
}

// ---------------- K4: pull-based GCN aggregate with BN1 affine folded ----------
// AGG[br][p][c] = sc[c] * sum_e w_e Y[br][src_e][c] + sh[c] * sum_e w_e
__global__ void pull_bn_kernel(const float* __restrict__ Y, const int* __restrict__ rowptr,
                               const int* __restrict__ csrs, const float* __restrict__ csrw,
                               const float* __restrict__ sc1, const float* __restrict__ sh1,
                               float* __restrict__ AGG)
{
    int id = blockIdx.x * 256 + threadIdx.x;
    if (id >= NND * 96) return;
    int br = blockIdx.y;
    int p = id / 96, c = id % 96;
    const size_t NM = (size_t)NND * 96;
    int beg = rowptr[p], end = rowptr[p + 1];
    float acc = 0.f, wsum = 0.f;
    const float* yb = Y + (size_t)br * NM;
    for (int i = beg; i < end; i++) {
        float w = csrw[i];
        acc += w * yb[(size_t)csrs[i] * 96 + c];
        wsum += w;
    }
    AGG[(size_t)br * NM + id] = sc1[br * 96 + c] * acc + sh1[br * 96 + c] * wsum;
}

// ---------------- pull-based gather (templated channel count) ----------------
template <int C>
__global__ void pull_kernel(const float* __restrict__ in, const int* __restrict__ rowptr,
                            const int* __restrict__ csrs, const float* __restrict__ csrw,
                            float* __restrict__ out)
{
    int id = blockIdx.x * 256 + threadIdx.x;
    if (id >= NND * C) return;
    int p = id / C, c = id % C;
    int beg = rowptr[p], end = rowptr[p + 1];
    float acc = 0.f;
    for (int i = beg; i < end; i++)
        acc += csrw[i] * in[(size_t)csrs[i] * C + c];
    out[id] = acc;
}

// ---------------- generic small matmul + bias + relu ----------------
__global__ void matmul_relu_kernel(const float* __restrict__ in, const float* __restrict__ W,
                                   const float* __restrict__ bias, float* __restrict__ out,
                                   int Cin, int Cout)
{
    int id = blockIdx.x * 256 + threadIdx.x;
    if (id >= NND * Cout) return;
    int p = id / Cout, o = id % Cout;
    float acc = bias[o];
    const float* row = in + (size_t)p * Cin;
    for (int c = 0; c < Cin; c++) acc += row[c] * W[c * Cout + o];
    out[id] = acc > 0.f ? acc : 0.f;
}

// ---------------- K6: press conv (3ch,K=3,SAME over 54) + BN2 stats ----------------
__global__ void press_stats_kernel(const float* __restrict__ H2, const float* __restrict__ pw,
                                   const float* __restrict__ pb, float* __restrict__ PRS,
                                   float* __restrict__ st2)
{
    __shared__ float ls[54], lq[54];
    int t = threadIdx.x;
    if (t < 54) { ls[t] = 0.f; lq[t] = 0.f; }
    __syncthreads();
    float pwf[9];
#pragma unroll
    for (int q = 0; q < 9; q++) pwf[q] = pw[q];
    float pbf = pb[0];
    const size_t NM = (size_t)NND * 54;
    size_t base = (size_t)blockIdx.x * 6912;
    for (int q = 0; q < 27; q++) {
        size_t idx = base + q * 256 + t;
        if (idx < NM) {
            int p = (int)(idx / 54), h = (int)(idx % 54);
            float sum = pbf;
#pragma unroll
            for (int i = 0; i < 3; i++)
#pragma unroll
                for (int k = 0; k < 3; k++) {
                    int hh = h + k - 1;
                    if (hh >= 0 && hh < 54)
                        sum += pwf[i * 3 + k] * H2[(size_t)i * NM + (size_t)p * 54 + hh];
                }
            PRS[idx] = sum;
            atomicAdd(&ls[h], sum); atomicAdd(&lq[h], sum * sum);
        }
    }
    __syncthreads();
    if (t < 54) {
        unsafeAtomicAdd(&st2[t], ls[t]);
        unsafeAtomicAdd(&st2[54 + t], lq[t]);
    }
}

// ---------------- K8: emd = affine(pressed); write fp32 out + keep fp32 ----------------
__global__ void emd_kernel(float* __restrict__ PRS, const float* __restrict__ sc2,
                           const float* __restrict__ sh2, float* __restrict__ outp)
{
    int id = blockIdx.x * 256 + threadIdx.x;
    if (id >= NND * 54) return;
    int h = id % 54;
    float v = PRS[id] * sc2[h] + sh2[h];
    PRS[id] = v;
    outp[id] = v;
}

// ---------------- K15: graph pooling of concat(h1,h2,h3) ----------------
__global__ void pool_kernel(const float* __restrict__ H1, const float* __restrict__ H2j,
                            const float* __restrict__ H3, const int* __restrict__ gid,
                            float* __restrict__ HG)
{
    int id = blockIdx.x * 256 + threadIdx.x;
    if (id >= NND * 75) return;
    int p = id / 75, c = id % 75;
    float v;
    if (c < 34)      v = H1[(size_t)p * 34 + c];
    else if (c < 59) v = H2j[(size_t)p * 25 + (c - 34)];
    else             v = H3[(size_t)p * 16 + (c - 59)];
    unsafeAtomicAdd(&HG[gid[p] * 75 + c], v);
}

// ---------------- K16: BN3 + cls matmuls, single block ----------------
__global__ void final_kernel(const float* __restrict__ HG, const float* __restrict__ g3,
                             const float* __restrict__ b3,
                             const float* __restrict__ w1, const float* __restrict__ b1,
                             const float* __restrict__ w2, const float* __restrict__ b2,
                             float* __restrict__ outp)
{
    __shared__ float hg[64 * 75];
    __shared__ float o1[64 * 120];
    __shared__ float sc[75], sh[75];
    int t = threadIdx.x;   // 512
    for (int idx = t; idx < 64 * 75; idx += 512) hg[idx] = HG[idx];
    __syncthreads();
    if (t < 75) {
        float s = 0.f, q = 0.f;
        for (int r = 0; r < 64; r++) { float v = hg[r * 75 + t]; s += v; q += v * v; }
        float m = s / 64.f, var = q / 64.f - m * m;
        float rs = rsqrtf(var + EPSV);
        float scale = g3[t] * rs;
        sc[t] = scale; sh[t] = b3[t] - m * scale;
    }
    __syncthreads();
    for (int idx = t; idx < 64 * 75; idx += 512) { int c = idx % 75; hg[idx] = hg[idx] * sc[c] + sh[c]; }
    __syncthreads();
    for (int idx = t; idx < 64 * 120; idx += 512) {
        int r = idx / 120, o = idx % 120;
        float a = b1[o];
        for (int c = 0; c < 75; c++) a += hg[r * 75 + c] * w1[c * 120 + o];
        o1[idx] = a;
    }
    __syncthreads();
    for (int idx = t; idx < 640; idx += 512) {
        int r = idx / 10, o = idx % 10;
        float a = b2[o];
        for (int k = 0; k < 120; k++) a += o1[r * 120 + k] * w2[k * 10 + o];
        outp[idx] = a;
    }
}

extern "C" void kernel_launch(void* const* d_in, const int* in_sizes, int n_in,
                              void* d_out, int out_size, void* d_ws, size_t ws_size,
                              hipStream_t stream)
{
    (void)in_sizes; (void)n_in; (void)out_size;
    const float* nf     = (const float*)d_in[0];
    const float* ew     = (const float*)d_in[1];
    const float* conv_w = (const float*)d_in[2];
    const float* conv_b = (const float*)d_in[3];
    const float* gcn_w  = (const float*)d_in[4];
    const float* gcn_b  = (const float*)d_in[5];
    const float* bn1_g = (const float*)d_in[6],  *bn1_b = (const float*)d_in[7];
    const float* bn2_g = (const float*)d_in[8],  *bn2_b = (const float*)d_in[9];
    const float* bn3_g = (const float*)d_in[10], *bn3_b = (const float*)d_in[11];
    const float* press_w = (const float*)d_in[12], *press_b = (const float*)d_in[13];
    const float* jk_w1 = (const float*)d_in[14], *jk_b1 = (const float*)d_in[15];
    const float* jk_w2 = (const float*)d_in[16], *jk_b2 = (const float*)d_in[17];
    const float* jk_w3 = (const float*)d_in[18], *jk_b3 = (const float*)d_in[19];
    const float* cls1_w = (const float*)d_in[20], *cls1_b = (const float*)d_in[21];
    const float* cls2_w = (const float*)d_in[22], *cls2_b = (const float*)d_in[23];
    const int* esrc = (const int*)d_in[24];
    const int* edst = (const int*)d_in[25];
    const int* gid  = (const int*)d_in[26];
    float* out = (float*)d_out;   // fp32 outputs: (logits[640], emd[2.7M])

    float* ws = (float*)d_ws;
    const size_t NM = (size_t)NND * 96;
    const size_t N54 = (size_t)NND * 54;
    float* X   = ws;                 // 3*NM   (aliased later: AGG)
    float* Y   = X + 3 * NM;         // 3*NM   (aliased later: jk buffers)
    float* H2c = Y + 3 * NM;         // 3*N54
    float* PRS = H2c + 3 * N54;      // N54
    float* ST1 = PRS + N54;          // 576
    float* SC1 = ST1 + 576;          // 288
    float* SH1 = SC1 + 288;          // 288
    float* ST2 = SH1 + 288;          // 108
    float* SC2 = ST2 + 108;          // 54
    float* SH2 = SC2 + 54;           // 54
    float* HG  = SH2 + 54;           // 4800
    // CSR-by-dst scratch
    int* CNT    = (int*)(HG + 4800);     // 50000
    int* ROWPTR = CNT + NND;             // 50001
    int* CURSOR = ROWPTR + NND + 1;      // 50000
    int* CSRS   = CURSOR + NND;          // 800000
    float* CSRW = (float*)(CSRS + NED);  // 800000
    size_t need = (size_t)((float*)(CSRW + NED) - ws) * sizeof(float);
    if (ws_size < need) return;      // ws too small -> fail loudly in validation

    // aliases
    float* AGG  = X;
    float* AGG1 = Y;                           // N*54
    float* H1j  = AGG1 + N54;                  // N*34
    float* AGG2 = H1j + (size_t)NND * 34;      // N*34
    float* H2j  = AGG2 + (size_t)NND * 34;     // N*25
    float* AGG3 = H2j + (size_t)NND * 25;      // N*25
    float* H3j  = AGG3 + (size_t)NND * 25;     // N*16

    // zero stats + HG (contiguous 6168 floats at ST1) and CSR histogram
    hipMemsetAsync(ST1, 0, 6168 * sizeof(float), stream);
    hipMemsetAsync(CNT, 0, NND * sizeof(int), stream);

    // CSR build (graph fixed per launch; reused by all 4 aggregation stages)
    hist_kernel<<<(NED + 255) / 256, 256, 0, stream>>>(edst, CNT);
    scan_kernel<<<1, 1024, 0, stream>>>(CNT, ROWPTR, CURSOR);
    fill_kernel<<<(NED + 255) / 256, 256, 0, stream>>>(esrc, edst, ew, CURSOR, CSRS, CSRW);

    // K1: dilated convs
    conv_kernel<<<dim3((NND + 255) / 256, 3, 3), 256, 0, stream>>>(nf, conv_w, conv_b, X);

    // K2/K3: Y + BN1
    y_stats_kernel<<<dim3((NND + 63) / 64, 3), 384, 0, stream>>>(X, Y, ST1);
    bn_finalize_kernel<<<1, 512, 0, stream>>>(ST1, bn1_g, bn1_b, SC1, SH1, 288, 96);

    // K4: pull-based GCN aggregate (X region reused as AGG; no memset needed)
    pull_bn_kernel<<<dim3((NND * 96 + 255) / 256, 3), 256, 0, stream>>>(
        Y, ROWPTR, CSRS, CSRW, SC1, SH1, AGG);

    // K5: GCN matmul + relu per branch
    for (int i = 0; i < 3; i++)
        matmul_relu_kernel<<<(int)((N54 + 255) / 256), 256, 0, stream>>>(
            AGG + (size_t)i * NM, gcn_w + (size_t)i * 96 * 54, gcn_b + i * 54,
            H2c + (size_t)i * N54, 96, 54);

    // K6/K7/K8: press + BN2 + emd out (fp32 at element offset 640)
    press_stats_kernel<<<(int)((N54 + 6911) / 6912), 256, 0, stream>>>(H2c, press_w, press_b, PRS, ST2);
    bn_finalize_kernel<<<1, 512, 0, stream>>>(ST2, bn2_g, bn2_b, SC2, SH2, 54, 54);
    emd_kernel<<<(int)((N54 + 255) / 256), 256, 0, stream>>>(PRS, SC2, SH2, out + 640);

    // JK layer 1 (Y region dead -> jk buffers)
    pull_kernel<54><<<(NND * 54 + 255) / 256, 256, 0, stream>>>(PRS, ROWPTR, CSRS, CSRW, AGG1);
    matmul_relu_kernel<<<(NND * 34 + 255) / 256, 256, 0, stream>>>(AGG1, jk_w1, jk_b1, H1j, 54, 34);

    // JK layer 2
    pull_kernel<34><<<(NND * 34 + 255) / 256, 256, 0, stream>>>(H1j, ROWPTR, CSRS, CSRW, AGG2);
    matmul_relu_kernel<<<(NND * 25 + 255) / 256, 256, 0, stream>>>(AGG2, jk_w2, jk_b2, H2j, 34, 25);

    // JK layer 3
    pull_kernel<25><<<(NND * 25 + 255) / 256, 256, 0, stream>>>(H2j, ROWPTR, CSRS, CSRW, AGG3);
    matmul_relu_kernel<<<(NND * 16 + 255) / 256, 256, 0, stream>>>(AGG3, jk_w3, jk_b3, H3j, 25, 16);

    // pooling + final
    pool_kernel<<<(NND * 75 + 255) / 256, 256, 0, stream>>>(H1j, H2j, H3j, gid, HG);
    final_kernel<<<1, 512, 0, stream>>>(HG, bn3_g, bn3_b, cls1_w, cls1_b, cls2_w, cls2_b, out);
}